// Round 2
// baseline (693.529 us; speedup 1.0000x reference)
//
#include <hip/hip_runtime.h>

// Scaled dot-product attention, B=8 H=12 S=1024 D=64, fp32 in/out.
// Outputs (concatenated in d_out): probs (B,H,S,S) then context (B,H,S,D).
//
// v3: occupancy-first restructure.
//  - 16-row Q tiles (grid 6144, 512 threads): LDS ~39KB, regs ~<128
//    -> 2-3 blocks/CU (was 1 block at 152KB LDS = the root serialization).
//  - sigma-permuted pl (slot s holds col (s&7)*16 + (s>>3) of the 128-col
//    span): probs->LDS is one bank-balanced ds_write_b128 per 8 values, and
//    PV B-fragments come DIRECTLY from global V at keys
//    k = sp*128 + j*16 + b2*4 + quad  (64B-coalesced, L2-resident),
//    deleting the vt transpose tile and ALL barriers inside the PV loop.
//  - PV split: 8 waves = (K-half kpar) x (4 d-tiles); ctx halves summed
//    through a small LDS buffer (one extra barrier).
//  - probs fp32 stores issued after the LAST barrier: no vmcnt(0) drain
//    ever blocks them; they retire under co-resident blocks' compute.
//  - XCD-clustered block remap: each XCD owns 12 whole bh's -> K/V L2-local.
//  - NT stores reverted (v2: WRITE_SIZE +35%, dur +7%).

#define SLEN 1024
#define DHEAD 64
#define NBH 96
#define QROWS 16

typedef __attribute__((ext_vector_type(4))) float f32x4;
typedef __attribute__((ext_vector_type(8))) __bf16 bf16x8;

#define PL_STRIDE 1032   // bf16; row = 2064 B = 129*16 (b128-aligned), 516 dw % 32 = 4

struct SMem {
  __bf16 pl[QROWS][PL_STRIDE];   // 33,024 B  probs bf16, sigma-permuted slots
  __bf16 qt[QROWS][72];          //  2,304 B  scaled Q tile (row = 144 B, 16B-aligned)
  float red[8][QROWS];           //    512 B  per-wave softmax partials
  float mrow[QROWS];             //     64 B
  float invrow[QROWS];           //     64 B
  float ctxr[4][64][4];          //  4,096 B  PV K-half partial sums
};                               // ~40,064 B -> 2+ blocks/CU

__global__ __launch_bounds__(512, 4)
void attn_fused(const float* __restrict__ Qp, const float* __restrict__ Kp,
                const float* __restrict__ Vp, const int* __restrict__ scale_p,
                float* __restrict__ out) {
  __shared__ SMem sm;
  const int tid  = threadIdx.x;
  const int w    = tid >> 6;     // wave 0..7
  const int lane = tid & 63;
  const int quad = lane >> 4;
  const int c16  = lane & 15;

  // XCD-clustered decode: assume XCD = bid % 8; each XCD owns 12 bh's.
  const int bid  = blockIdx.x;             // 0..6143
  const int xcd  = bid & 7;
  const int slot = bid >> 3;               // 0..767
  const int bh   = xcd * 12 + (slot >> 6); // 12 bh per XCD, 64 qtiles each
  const int qbase = (slot & 63) * QROWS;

  // scale arrives as a 1-element array; robust to int32 or fp32 encoding
  int siv = *scale_p;
  float fs = (siv >= 1 && siv <= (1 << 24)) ? (float)siv : __int_as_float(siv);
  const float inv_scale = 1.0f / fs;

  const float* Qg = Qp + ((size_t)bh * SLEN + qbase) * DHEAD;
  const float* Kg = Kp + (size_t)bh * SLEN * DHEAD;
  const float* Vg = Vp + (size_t)bh * SLEN * DHEAD;

  // ---- stage Q tile (x 1/scale) to LDS as bf16: 16x64 fp32 = 256 f32x4 ----
  if (tid < 256) {
    int r = tid >> 4, d = (tid & 15) * 4;
    f32x4 qv = *(const f32x4*)(Qg + (size_t)r * DHEAD + d);
    #pragma unroll
    for (int j = 0; j < 4; ++j) sm.qt[r][d + j] = (__bf16)(qv[j] * inv_scale);
  }
  __syncthreads();

  // A-frags: A[m=lane&15][k=quad*8+j]
  bf16x8 af[2];
  #pragma unroll
  for (int k0 = 0; k0 < 2; ++k0)
    af[k0] = *(const bf16x8*)&sm.qt[c16][k0 * 32 + quad * 8];

  f32x4 acc[8];
  {
    f32x4 z = {0.0f, 0.0f, 0.0f, 0.0f};
    #pragma unroll
    for (int ct = 0; ct < 8; ++ct) acc[ct] = z;
  }

  // ---- phase 1: S = (Q/scale) K^T.  Wave w owns key cols [w*128, w*128+128) ----
  #pragma unroll
  for (int ct = 0; ct < 8; ++ct) {
    int krow = w * 128 + ct * 16 + c16;   // B-frag: B[k=quad*8+j][n=lane&15] = K[n][k]
    const float* kr = Kg + (size_t)krow * DHEAD + quad * 8;
    f32x4 k0a = *(const f32x4*)(kr);
    f32x4 k0b = *(const f32x4*)(kr + 4);
    f32x4 k1a = *(const f32x4*)(kr + 32);
    f32x4 k1b = *(const f32x4*)(kr + 36);
    bf16x8 b0, b1;
    #pragma unroll
    for (int j = 0; j < 4; ++j) {
      b0[j]     = (__bf16)k0a[j];
      b0[j + 4] = (__bf16)k0b[j];
      b1[j]     = (__bf16)k1a[j];
      b1[j + 4] = (__bf16)k1b[j];
    }
    acc[ct] = __builtin_amdgcn_mfma_f32_16x16x32_bf16(af[0], b0, acc[ct], 0, 0, 0);
    acc[ct] = __builtin_amdgcn_mfma_f32_16x16x32_bf16(af[1], b1, acc[ct], 0, 0, 0);
  }

  // ---- softmax: row max (C/D: row = quad*4 + i, col = lane&15) ----
  float mx[4];
  #pragma unroll
  for (int i = 0; i < 4; ++i) {
    float m = acc[0][i];
    #pragma unroll
    for (int ct = 1; ct < 8; ++ct) m = fmaxf(m, acc[ct][i]);
    mx[i] = m;
  }
  #pragma unroll
  for (int off = 1; off < 16; off <<= 1)
    #pragma unroll
    for (int i = 0; i < 4; ++i)
      mx[i] = fmaxf(mx[i], __shfl_xor(mx[i], off));
  if (c16 == 0) {
    #pragma unroll
    for (int i = 0; i < 4; ++i) sm.red[w][quad * 4 + i] = mx[i];
  }
  __syncthreads();
  if (tid < QROWS) {
    float m = sm.red[0][tid];
    #pragma unroll
    for (int w2 = 1; w2 < 8; ++w2) m = fmaxf(m, sm.red[w2][tid]);
    sm.mrow[tid] = m;
  }
  __syncthreads();

  // ---- exp + row sum ----
  float sum4[4];
  #pragma unroll
  for (int i = 0; i < 4; ++i) {
    float m = sm.mrow[quad * 4 + i];
    float s = 0.0f;
    #pragma unroll
    for (int ct = 0; ct < 8; ++ct) {
      float e = __expf(acc[ct][i] - m);
      acc[ct][i] = e;
      s += e;
    }
    sum4[i] = s;
  }
  #pragma unroll
  for (int off = 1; off < 16; off <<= 1)
    #pragma unroll
    for (int i = 0; i < 4; ++i)
      sum4[i] += __shfl_xor(sum4[i], off);
  if (c16 == 0) {
    #pragma unroll
    for (int i = 0; i < 4; ++i) sm.red[w][quad * 4 + i] = sum4[i];
  }
  __syncthreads();
  if (tid < QROWS) {
    float s = 0.0f;
    #pragma unroll
    for (int w2 = 0; w2 < 8; ++w2) s += sm.red[w2][tid];
    sm.invrow[tid] = 1.0f / s;
  }
  __syncthreads();

  // ---- phase 3: normalize in regs; bf16 -> LDS sigma-permuted (b128) ----
  // pl[row][w*128 + c16*8 + ct] = P[row][w*128 + ct*16 + c16]
  #pragma unroll
  for (int i = 0; i < 4; ++i) {
    int row = quad * 4 + i;
    float inv = sm.invrow[row];
    bf16x8 pk;
    #pragma unroll
    for (int ct = 0; ct < 8; ++ct) {
      float p = acc[ct][i] * inv;
      acc[ct][i] = p;               // keep normalized value for the global store
      pk[ct] = (__bf16)p;
    }
    *(bf16x8*)&sm.pl[row][w * 128 + c16 * 8] = pk;
  }
  __syncthreads();   // no outstanding vmem here -> cheap barrier

  // ---- phase 4: context = P @ V, V fragments DIRECT from global ----
  // Wave w -> kpar = w>>2 (spans kpar*4 .. kpar*4+3), dt = w&3.
  // Slot s = b2*32 + quad*8 + j holds key  sp*128 + j*16 + b2*4 + quad.
  const int kpar = w >> 2;
  const int dt   = w & 3;
  const float* Vb = Vg + dt * 16 + c16;

  f32x4 ctx = {0.0f, 0.0f, 0.0f, 0.0f};
  float vr0[8], vr1[8];
  bf16x8 pa0, pa1;

  auto ldv = [&](float (&dst)[8], int itl) {
    int kb = (kpar * 4 + (itl >> 2)) * 128 + (itl & 3) * 4 + quad;
    #pragma unroll
    for (int j = 0; j < 8; ++j)
      dst[j] = Vb[(size_t)((kb + j * 16) * DHEAD)];
  };
  auto lda = [&](bf16x8& d, int itl) {
    d = *(const bf16x8*)&sm.pl[c16][(kpar * 4 + (itl >> 2)) * 128 +
                                    (itl & 3) * 32 + quad * 8];
  };

  ldv(vr0, 0); lda(pa0, 0);
  #pragma unroll
  for (int it = 0; it < 16; it += 2) {
    ldv(vr1, it + 1); lda(pa1, it + 1);   // prefetch next while current computes
    bf16x8 bf0;
    #pragma unroll
    for (int j = 0; j < 8; ++j) bf0[j] = (__bf16)vr0[j];
    ctx = __builtin_amdgcn_mfma_f32_16x16x32_bf16(pa0, bf0, ctx, 0, 0, 0);
    if (it + 2 < 16) { ldv(vr0, it + 2); lda(pa0, it + 2); }
    bf16x8 bf1;
    #pragma unroll
    for (int j = 0; j < 8; ++j) bf1[j] = (__bf16)vr1[j];
    ctx = __builtin_amdgcn_mfma_f32_16x16x32_bf16(pa1, bf1, ctx, 0, 0, 0);
  }

  // ---- reduce the two K-halves and write context ----
  if (kpar == 1) *(f32x4*)&sm.ctxr[dt][lane][0] = ctx;
  __syncthreads();   // LAST barrier of the kernel
  if (kpar == 0) {
    f32x4 o = *(const f32x4*)&sm.ctxr[dt][lane][0];
    float* outC = out + (size_t)NBH * SLEN * SLEN;
    #pragma unroll
    for (int i = 0; i < 4; ++i) {
      float r = ctx[i] + o[i];
      outC[((size_t)bh * SLEN + qbase + quad * 4 + i) * DHEAD + dt * 16 + c16] = r;
    }
  }

  // ---- probs fp32 -> global from regs; after all barriers, drains at end ----
  #pragma unroll
  for (int i = 0; i < 4; ++i) {
    int row = quad * 4 + i;
    float* orow = out + ((size_t)bh * SLEN + qbase + row) * SLEN;
    #pragma unroll
    for (int ct = 0; ct < 8; ++ct)
      orow[w * 128 + ct * 16 + c16] = acc[ct][i];
  }
}

extern "C" void kernel_launch(void* const* d_in, const int* in_sizes, int n_in,
                              void* d_out, int out_size, void* d_ws, size_t ws_size,
                              hipStream_t stream) {
  (void)in_sizes; (void)n_in; (void)d_ws; (void)ws_size; (void)out_size;
  const float* q = (const float*)d_in[0];
  const float* k = (const float*)d_in[1];
  const float* v = (const float*)d_in[2];
  const int* scale = (const int*)d_in[3];
  float* out = (float*)d_out;
  dim3 grid((SLEN / QROWS) * NBH);   // 6144, XCD-clustered decode in-kernel
  dim3 block(512);
  hipLaunchKernelGGL(attn_fused, grid, block, 0, stream, q, k, v, scale, out);
}